// Round 1
// baseline (546.019 us; speedup 1.0000x reference)
//
#include <hip/hip_runtime.h>

static inline int cdiv(int a, int b) { return (a + b - 1) / b; }

// ---------------- degree + norm ----------------
__global__ __launch_bounds__(256) void k_deg(const int* __restrict__ dst, int E, int* __restrict__ deg) {
    int e = blockIdx.x * 256 + threadIdx.x;
    if (e < E) atomicAdd(&deg[dst[e]], 1);
}

__global__ __launch_bounds__(256) void k_dinv(const int* __restrict__ deg, float* __restrict__ dinv, int N) {
    int i = blockIdx.x * 256 + threadIdx.x;
    if (i < N) dinv[i] = rsqrtf((float)(deg[i] + 1));  // +1 self loop; always >= 1
}

// ---------------- exclusive scan (hierarchical) ----------------
#define SCAN_BS 1024

__global__ __launch_bounds__(SCAN_BS) void k_blocksum(const int* __restrict__ deg, int N, int* __restrict__ bsum) {
    __shared__ int s[SCAN_BS];
    int t = threadIdx.x;
    int i = blockIdx.x * SCAN_BS + t;
    s[t] = (i < N) ? deg[i] : 0;
    __syncthreads();
    for (int off = SCAN_BS / 2; off > 0; off >>= 1) {
        if (t < off) s[t] += s[t + off];
        __syncthreads();
    }
    if (t == 0) bsum[blockIdx.x] = s[0];
}

__global__ __launch_bounds__(128) void k_scan_bsums(const int* __restrict__ bsum, int NB, int* __restrict__ boff) {
    // single block, NB <= 128
    __shared__ int s[128];
    int t = threadIdx.x;
    int v = (t < NB) ? bsum[t] : 0;
    s[t] = v;
    __syncthreads();
    for (int off = 1; off < 128; off <<= 1) {
        int u = (t >= off) ? s[t - off] : 0;
        __syncthreads();
        s[t] += u;
        __syncthreads();
    }
    if (t < NB) boff[t] = s[t] - v;  // exclusive
}

__global__ __launch_bounds__(SCAN_BS) void k_scan_final(const int* __restrict__ deg, int N,
                                                        const int* __restrict__ boff,
                                                        int* __restrict__ offsets, int* __restrict__ cursor, int E) {
    __shared__ int s[SCAN_BS];
    int t = threadIdx.x;
    int i = blockIdx.x * SCAN_BS + t;
    int v = (i < N) ? deg[i] : 0;
    s[t] = v;
    __syncthreads();
    for (int off = 1; off < SCAN_BS; off <<= 1) {
        int u = (t >= off) ? s[t - off] : 0;
        __syncthreads();
        s[t] += u;
        __syncthreads();
    }
    if (i < N) {
        int ex = boff[blockIdx.x] + s[t] - v;
        offsets[i] = ex;
        cursor[i] = ex;
    }
    if (blockIdx.x == 0 && t == 0) offsets[N] = E;  // total = E exactly
}

// ---------------- CSR build ----------------
__global__ __launch_bounds__(256) void k_csr_build(const int* __restrict__ ei, int E,
                                                   const float* __restrict__ dinv,
                                                   int* __restrict__ cursor,
                                                   int* __restrict__ csr_src, float* __restrict__ csr_norm) {
    int e = blockIdx.x * 256 + threadIdx.x;
    if (e >= E) return;
    int s = ei[e];
    int d = ei[E + e];
    int p = atomicAdd(&cursor[d], 1);
    csr_src[p] = s;
    csr_norm[p] = dinv[s] * dinv[d];
}

// ---------------- aggregation: out[g] = sum_{e in in(g)} feat[src]*norm + feat[g]*dinv[g]^2 ----------------
template <int F>
__global__ __launch_bounds__(256) void k_agg(const float* __restrict__ feat,
                                             const int* __restrict__ offsets,
                                             const int* __restrict__ csr_src, const float* __restrict__ csr_norm,
                                             const float* __restrict__ dinv,
                                             float* __restrict__ out, int N) {
    int t = blockIdx.x * 256 + threadIdx.x;
    int g = t / F;       // node
    int f = t & (F - 1); // feature
    if (g >= N) return;
    int beg = offsets[g];
    int end = offsets[g + 1];
    float di = dinv[g];
    float acc = feat[(size_t)g * F + f] * (di * di);  // self loop
    for (int e = beg; e < end; ++e) {
        acc = fmaf(feat[(size_t)csr_src[e] * F + f], csr_norm[e], acc);
    }
    out[(size_t)g * F + f] = acc;
}

// ---------------- GEMM1: h2 = relu(A[Nx32] @ W[32x64] + b), 4 rows x 64 cols per block ----------------
__global__ __launch_bounds__(256) void k_gemm1(const float* __restrict__ A, const float* __restrict__ W,
                                               const float* __restrict__ b, float* __restrict__ out, int N) {
    __shared__ float sW[32 * 64];
    __shared__ float sB[64];
    __shared__ float sX[4][32];
    int tid = threadIdx.x;
#pragma unroll
    for (int i = 0; i < 8; ++i) sW[tid + 256 * i] = W[tid + 256 * i];
    if (tid < 64) sB[tid] = b[tid];
    if (tid < 128) {
        int rr = tid >> 5, k = tid & 31;
        int rw = blockIdx.x * 4 + rr;
        sX[rr][k] = (rw < N) ? A[(size_t)rw * 32 + k] : 0.f;
    }
    __syncthreads();
    int r = tid >> 6, c = tid & 63;
    int row = blockIdx.x * 4 + r;
    float acc = sB[c];
#pragma unroll
    for (int k = 0; k < 32; ++k) acc = fmaf(sX[r][k], sW[k * 64 + c], acc);
    if (row < N) out[(size_t)row * 64 + c] = fmaxf(acc, 0.f);
}

// ---------------- GEMM2: out = A[Nx64] @ W[64x128] + b, 2 rows x 128 cols per block ----------------
__global__ __launch_bounds__(256) void k_gemm2(const float* __restrict__ A, const float* __restrict__ W,
                                               const float* __restrict__ b, float* __restrict__ out, int N) {
    __shared__ float sW[64 * 128];
    __shared__ float sB[128];
    __shared__ float sX[2][64];
    int tid = threadIdx.x;
#pragma unroll
    for (int i = 0; i < 32; ++i) sW[tid + 256 * i] = W[tid + 256 * i];
    if (tid < 128) sB[tid] = b[tid];
    if (tid < 128) {
        int rr = tid >> 6, k = tid & 63;
        int rw = blockIdx.x * 2 + rr;
        sX[rr][k] = (rw < N) ? A[(size_t)rw * 64 + k] : 0.f;
    }
    __syncthreads();
    int r = tid >> 7, c = tid & 127;
    int row = blockIdx.x * 2 + r;
    float acc = sB[c];
#pragma unroll
    for (int k = 0; k < 64; ++k) acc = fmaf(sX[r][k], sW[k * 128 + c], acc);
    if (row < N) out[(size_t)row * 128 + c] = acc;
}

extern "C" void kernel_launch(void* const* d_in, const int* in_sizes, int n_in,
                              void* d_out, int out_size, void* d_ws, size_t ws_size,
                              hipStream_t stream) {
    const float* x  = (const float*)d_in[0];
    const int*   ei = (const int*)d_in[1];   // [2, E] : src row then dst row
    const float* W1 = (const float*)d_in[2];
    const float* b1 = (const float*)d_in[3];
    const float* W2 = (const float*)d_in[4];
    const float* b2 = (const float*)d_in[5];
    float* out = (float*)d_out;

    const int N = in_sizes[0] / 32;
    const int E = in_sizes[1] / 2;

    char* ws = (char*)d_ws;
    size_t off = 0;
    auto walloc = [&](size_t bytes) -> void* {
        void* p = ws + off;
        off = (off + bytes + 255) & ~(size_t)255;
        return p;
    };
    int*   deg     = (int*)  walloc((size_t)N * 4);
    float* dinv    = (float*)walloc((size_t)N * 4);
    int*   offsets = (int*)  walloc((size_t)(N + 1) * 4);
    int*   cursor  = (int*)  walloc((size_t)N * 4);
    int*   bsum    = (int*)  walloc(128 * 4);
    int*   boff    = (int*)  walloc(128 * 4);
    int*   csr_src = (int*)  walloc((size_t)E * 4);
    float* csr_nrm = (float*)walloc((size_t)E * 4);
    float* a1      = (float*)walloc((size_t)N * 32 * 4);
    float* h2      = (float*)walloc((size_t)N * 64 * 4);
    float* a2      = (float*)walloc((size_t)N * 64 * 4);
    (void)ws_size; (void)n_in; (void)out_size;

    hipMemsetAsync(deg, 0, (size_t)N * 4, stream);

    k_deg<<<cdiv(E, 256), 256, 0, stream>>>(ei + E, E, deg);
    k_dinv<<<cdiv(N, 256), 256, 0, stream>>>(deg, dinv, N);

    const int NB = cdiv(N, SCAN_BS);  // 98 for N=100000, must be <= 128
    k_blocksum<<<NB, SCAN_BS, 0, stream>>>(deg, N, bsum);
    k_scan_bsums<<<1, 128, 0, stream>>>(bsum, NB, boff);
    k_scan_final<<<NB, SCAN_BS, 0, stream>>>(deg, N, boff, offsets, cursor, E);

    k_csr_build<<<cdiv(E, 256), 256, 0, stream>>>(ei, E, dinv, cursor, csr_src, csr_nrm);

    // layer 1: agg(x) [N x 32] -> gemm+bias+relu -> h2 [N x 64]
    k_agg<32><<<cdiv(N * 32, 256), 256, 0, stream>>>(x, offsets, csr_src, csr_nrm, dinv, a1, N);
    k_gemm1<<<cdiv(N, 4), 256, 0, stream>>>(a1, W1, b1, h2, N);

    // layer 2: agg(h2) [N x 64] -> gemm+bias -> out [N x 128]
    k_agg<64><<<cdiv(N * 64, 256), 256, 0, stream>>>(h2, offsets, csr_src, csr_nrm, dinv, a2, N);
    k_gemm2<<<cdiv(N, 2), 256, 0, stream>>>(a2, W2, b2, out, N);
}

// Round 2
// 405.873 us; speedup vs baseline: 1.3453x; 1.3453x over previous
//
#include <hip/hip_runtime.h>

static inline int cdiv(int a, int b) { return (a + b - 1) / b; }

// ---------------- degree + norm ----------------
__global__ __launch_bounds__(256) void k_deg(const int* __restrict__ dst, int E, int* __restrict__ deg) {
    int e = blockIdx.x * 256 + threadIdx.x;
    if (e < E) atomicAdd(&deg[dst[e]], 1);
}

__global__ __launch_bounds__(256) void k_dinv(const int* __restrict__ deg, float* __restrict__ dinv, int N) {
    int i = blockIdx.x * 256 + threadIdx.x;
    if (i < N) dinv[i] = rsqrtf((float)(deg[i] + 1));  // +1 self loop; always >= 1
}

// ---------------- exclusive scan (hierarchical) ----------------
#define SCAN_BS 1024

__global__ __launch_bounds__(SCAN_BS) void k_blocksum(const int* __restrict__ deg, int N, int* __restrict__ bsum) {
    __shared__ int s[SCAN_BS];
    int t = threadIdx.x;
    int i = blockIdx.x * SCAN_BS + t;
    s[t] = (i < N) ? deg[i] : 0;
    __syncthreads();
    for (int off = SCAN_BS / 2; off > 0; off >>= 1) {
        if (t < off) s[t] += s[t + off];
        __syncthreads();
    }
    if (t == 0) bsum[blockIdx.x] = s[0];
}

__global__ __launch_bounds__(128) void k_scan_bsums(const int* __restrict__ bsum, int NB, int* __restrict__ boff) {
    // single block, NB <= 128
    __shared__ int s[128];
    int t = threadIdx.x;
    int v = (t < NB) ? bsum[t] : 0;
    s[t] = v;
    __syncthreads();
    for (int off = 1; off < 128; off <<= 1) {
        int u = (t >= off) ? s[t - off] : 0;
        __syncthreads();
        s[t] += u;
        __syncthreads();
    }
    if (t < NB) boff[t] = s[t] - v;  // exclusive
}

__global__ __launch_bounds__(SCAN_BS) void k_scan_final(const int* __restrict__ deg, int N,
                                                        const int* __restrict__ boff,
                                                        int* __restrict__ offsets, int* __restrict__ cursor, int E) {
    __shared__ int s[SCAN_BS];
    int t = threadIdx.x;
    int i = blockIdx.x * SCAN_BS + t;
    int v = (i < N) ? deg[i] : 0;
    s[t] = v;
    __syncthreads();
    for (int off = 1; off < SCAN_BS; off <<= 1) {
        int u = (t >= off) ? s[t - off] : 0;
        __syncthreads();
        s[t] += u;
        __syncthreads();
    }
    if (i < N) {
        int ex = boff[blockIdx.x] + s[t] - v;
        offsets[i] = ex;
        cursor[i] = ex;
    }
    if (blockIdx.x == 0 && t == 0) offsets[N] = E;  // total = E exactly
}

// ---------------- CSR build (packed int2 {src, norm-as-bits}) ----------------
__global__ __launch_bounds__(256) void k_csr_build(const int* __restrict__ ei, int E,
                                                   const float* __restrict__ dinv,
                                                   int* __restrict__ cursor,
                                                   int2* __restrict__ csr) {
    int e = blockIdx.x * 256 + threadIdx.x;
    if (e >= E) return;
    int s = ei[e];
    int d = ei[E + e];
    int p = atomicAdd(&cursor[d], 1);
    float nrm = dinv[s] * dinv[d];
    csr[p] = make_int2(s, __float_as_int(nrm));
}

// ---------------- aggregation: out[g] = sum_{e in in(g)} feat[src]*norm + feat[g]*dinv[g]^2 ----------------
// Unrolled x8: 8 packed index loads then 8 independent row-gathers in flight.
template <int F>
__global__ __launch_bounds__(256) void k_agg(const float* __restrict__ feat,
                                             const int* __restrict__ offsets,
                                             const int2* __restrict__ csr,
                                             const float* __restrict__ dinv,
                                             float* __restrict__ out, int N) {
    int t = blockIdx.x * 256 + threadIdx.x;
    int g = t / F;       // node
    int f = t & (F - 1); // feature
    if (g >= N) return;
    int beg = offsets[g];
    int end = offsets[g + 1];
    float di = dinv[g];
    float acc = feat[g * F + f] * (di * di);  // self loop
    int e = beg;
    for (; e + 8 <= end; e += 8) {
        int2 p0 = csr[e + 0], p1 = csr[e + 1], p2 = csr[e + 2], p3 = csr[e + 3];
        int2 p4 = csr[e + 4], p5 = csr[e + 5], p6 = csr[e + 6], p7 = csr[e + 7];
        float v0 = feat[p0.x * F + f];
        float v1 = feat[p1.x * F + f];
        float v2 = feat[p2.x * F + f];
        float v3 = feat[p3.x * F + f];
        float v4 = feat[p4.x * F + f];
        float v5 = feat[p5.x * F + f];
        float v6 = feat[p6.x * F + f];
        float v7 = feat[p7.x * F + f];
        acc = fmaf(v0, __int_as_float(p0.y), acc);
        acc = fmaf(v1, __int_as_float(p1.y), acc);
        acc = fmaf(v2, __int_as_float(p2.y), acc);
        acc = fmaf(v3, __int_as_float(p3.y), acc);
        acc = fmaf(v4, __int_as_float(p4.y), acc);
        acc = fmaf(v5, __int_as_float(p5.y), acc);
        acc = fmaf(v6, __int_as_float(p6.y), acc);
        acc = fmaf(v7, __int_as_float(p7.y), acc);
    }
    for (; e + 2 <= end; e += 2) {
        int2 p0 = csr[e + 0], p1 = csr[e + 1];
        float v0 = feat[p0.x * F + f];
        float v1 = feat[p1.x * F + f];
        acc = fmaf(v0, __int_as_float(p0.y), acc);
        acc = fmaf(v1, __int_as_float(p1.y), acc);
    }
    if (e < end) {
        int2 p0 = csr[e];
        acc = fmaf(feat[p0.x * F + f], __int_as_float(p0.y), acc);
    }
    out[g * F + f] = acc;
}

// ---------------- GEMM1: h2 = relu(A[Nx32] @ W[32x64] + b), 4 rows x 64 cols per block ----------------
__global__ __launch_bounds__(256) void k_gemm1(const float* __restrict__ A, const float* __restrict__ W,
                                               const float* __restrict__ b, float* __restrict__ out, int N) {
    __shared__ float sW[32 * 64];
    __shared__ float sB[64];
    __shared__ float sX[4][32];
    int tid = threadIdx.x;
#pragma unroll
    for (int i = 0; i < 8; ++i) sW[tid + 256 * i] = W[tid + 256 * i];
    if (tid < 64) sB[tid] = b[tid];
    if (tid < 128) {
        int rr = tid >> 5, k = tid & 31;
        int rw = blockIdx.x * 4 + rr;
        sX[rr][k] = (rw < N) ? A[(size_t)rw * 32 + k] : 0.f;
    }
    __syncthreads();
    int r = tid >> 6, c = tid & 63;
    int row = blockIdx.x * 4 + r;
    float acc = sB[c];
#pragma unroll
    for (int k = 0; k < 32; ++k) acc = fmaf(sX[r][k], sW[k * 64 + c], acc);
    if (row < N) out[(size_t)row * 64 + c] = fmaxf(acc, 0.f);
}

// ---------------- GEMM2: out = A[Nx64] @ W[64x128] + b, 2 rows x 128 cols per block ----------------
__global__ __launch_bounds__(256) void k_gemm2(const float* __restrict__ A, const float* __restrict__ W,
                                               const float* __restrict__ b, float* __restrict__ out, int N) {
    __shared__ float sW[64 * 128];
    __shared__ float sB[128];
    __shared__ float sX[2][64];
    int tid = threadIdx.x;
#pragma unroll
    for (int i = 0; i < 32; ++i) sW[tid + 256 * i] = W[tid + 256 * i];
    if (tid < 128) sB[tid] = b[tid];
    if (tid < 128) {
        int rr = tid >> 6, k = tid & 63;
        int rw = blockIdx.x * 2 + rr;
        sX[rr][k] = (rw < N) ? A[(size_t)rw * 64 + k] : 0.f;
    }
    __syncthreads();
    int r = tid >> 7, c = tid & 127;
    int row = blockIdx.x * 2 + r;
    float acc = sB[c];
#pragma unroll
    for (int k = 0; k < 64; ++k) acc = fmaf(sX[r][k], sW[k * 128 + c], acc);
    if (row < N) out[(size_t)row * 128 + c] = acc;
}

extern "C" void kernel_launch(void* const* d_in, const int* in_sizes, int n_in,
                              void* d_out, int out_size, void* d_ws, size_t ws_size,
                              hipStream_t stream) {
    const float* x  = (const float*)d_in[0];
    const int*   ei = (const int*)d_in[1];   // [2, E] : src row then dst row
    const float* W1 = (const float*)d_in[2];
    const float* b1 = (const float*)d_in[3];
    const float* W2 = (const float*)d_in[4];
    const float* b2 = (const float*)d_in[5];
    float* out = (float*)d_out;

    const int N = in_sizes[0] / 32;
    const int E = in_sizes[1] / 2;

    char* ws = (char*)d_ws;
    size_t off = 0;
    auto walloc = [&](size_t bytes) -> void* {
        void* p = ws + off;
        off = (off + bytes + 255) & ~(size_t)255;
        return p;
    };
    int*   deg     = (int*)  walloc((size_t)N * 4);
    float* dinv    = (float*)walloc((size_t)N * 4);
    int*   offsets = (int*)  walloc((size_t)(N + 1) * 4);
    int*   cursor  = (int*)  walloc((size_t)N * 4);
    int*   bsum    = (int*)  walloc(128 * 4);
    int*   boff    = (int*)  walloc(128 * 4);
    int2*  csr     = (int2*) walloc((size_t)E * 8);
    float* a1      = (float*)walloc((size_t)N * 32 * 4);
    float* h2      = (float*)walloc((size_t)N * 64 * 4);
    float* a2      = (float*)walloc((size_t)N * 64 * 4);
    (void)ws_size; (void)n_in; (void)out_size;

    hipMemsetAsync(deg, 0, (size_t)N * 4, stream);

    k_deg<<<cdiv(E, 256), 256, 0, stream>>>(ei + E, E, deg);
    k_dinv<<<cdiv(N, 256), 256, 0, stream>>>(deg, dinv, N);

    const int NB = cdiv(N, SCAN_BS);  // 98 for N=100000, must be <= 128
    k_blocksum<<<NB, SCAN_BS, 0, stream>>>(deg, N, bsum);
    k_scan_bsums<<<1, 128, 0, stream>>>(bsum, NB, boff);
    k_scan_final<<<NB, SCAN_BS, 0, stream>>>(deg, N, boff, offsets, cursor, E);

    k_csr_build<<<cdiv(E, 256), 256, 0, stream>>>(ei, E, dinv, cursor, csr);

    // layer 1: agg(x) [N x 32] -> gemm+bias+relu -> h2 [N x 64]
    k_agg<32><<<cdiv(N * 32, 256), 256, 0, stream>>>(x, offsets, csr, dinv, a1, N);
    k_gemm1<<<cdiv(N, 4), 256, 0, stream>>>(a1, W1, b1, h2, N);

    // layer 2: agg(h2) [N x 64] -> gemm+bias -> out [N x 128]
    k_agg<64><<<cdiv(N * 64, 256), 256, 0, stream>>>(h2, offsets, csr, dinv, a2, N);
    k_gemm2<<<cdiv(N, 2), 256, 0, stream>>>(a2, W2, b2, out, N);
}